// Round 6
// baseline (95.595 us; speedup 1.0000x reference)
//
#include <hip/hip_runtime.h>

// Cubic B-spline prefilter (Unser), periodic, axes 2,3,4 of (2,3,160,160,160) fp32.
//
// pass_d2   : axis-2 IIR (element stride 160^2). v2: each thread handles 4
//   adjacent lines via float4 (1 KB/wave-load burst, 4x ILP), 20-output chunks
//   (8 chunks/line), 16-step truncated warm-up, and the "T-trick" anticausal
//   init (accumulate T = sum z^{k+1} c+(tail) on the fly -> no cp[] array,
//   state = f4[20]+st+T ~ 94 VGPR, no spill). in -> ws.
// slab_d3d4 : axes 3+4 fused (validated R4). 320-thread block owns a 40x160
//   slab of a contiguous (d3,d4) plane: d3 sweep streams global reads into
//   registers, publishes to 25.6 KB swizzled LDS, d4 sweep from LDS, coalesced
//   store. ws -> out.
// Fallback (ws too small): R3-validated in-place full-plane kernel.

#define NAX   160
#define PLN   25600      // 160*160
#define VOL   4096000    // 160*PLN
#define GPP   6400       // float4 groups per plane (PLN/4)
#define ZP    (-0.26794919243112270647f)   // sqrt(3)-2
#define KW    16         // truncated warm-up (z^16 ~ 7.4e-10)

// ---------------- Kernel A: axis-2, float4 x 4-line register IIR ------------
__global__ __launch_bounds__(256, 3)
void pass_d2(const float* __restrict__ in, float* __restrict__ out)
{
    const float z = ZP;
    const int lane  = threadIdx.x & 63;
    const int wv    = threadIdx.x >> 6;               // 0..3
    const int chunk = ((blockIdx.x & 1) << 2) | wv;   // 0..7
    const int lg    = (blockIdx.x >> 1) * 64 + lane;  // line-group 0..38399
    const int v     = lg / GPP;                       // volume 0..5
    const int i4    = lg - v * GPP;                   // float4 index in plane
    const float4* src = reinterpret_cast<const float4*>(in)  + (size_t)v * (VOL / 4) + i4;
    float4*       dst = reinterpret_cast<float4*>(out)       + (size_t)v * (VOL / 4) + i4;
    const int n0 = chunk * 20;

    float4 st = make_float4(0.f, 0.f, 0.f, 0.f);

    // causal warm-up (16 rows, periodic wrap)
    #pragma unroll
    for (int s = 0; s < KW; ++s) {
        int r = n0 - KW + s; if (r < 0) r += NAX;
        const float4 x = src[(size_t)r * GPP];
        st.x = fmaf(z, st.x, 6.0f * x.x);
        st.y = fmaf(z, st.y, 6.0f * x.y);
        st.z = fmaf(z, st.z, 6.0f * x.z);
        st.w = fmaf(z, st.w, 6.0f * x.w);
    }
    // causal outputs (20 rows, never wraps: n0+19 <= 159)
    float4 f[20];
    #pragma unroll
    for (int s = 0; s < 20; ++s) {
        const float4 x = src[(size_t)(n0 + s) * GPP];
        st.x = fmaf(z, st.x, 6.0f * x.x);
        st.y = fmaf(z, st.y, 6.0f * x.y);
        st.z = fmaf(z, st.z, 6.0f * x.z);
        st.w = fmaf(z, st.w, 6.0f * x.w);
        f[s] = st;
    }
    // tail (16 rows): extend c+ and accumulate T = sum_k z^{k+1} c+(n0+20+k)
    // => c-(n0+20) = -T  (truncated anticausal init; z^17 ~ 2e-10)
    float4 T = make_float4(0.f, 0.f, 0.f, 0.f);
    float zp = z;
    #pragma unroll
    for (int k = 0; k < KW; ++k) {
        int r = n0 + 20 + k; if (r >= NAX) r -= NAX;
        const float4 x = src[(size_t)r * GPP];
        st.x = fmaf(z, st.x, 6.0f * x.x);
        st.y = fmaf(z, st.y, 6.0f * x.y);
        st.z = fmaf(z, st.z, 6.0f * x.z);
        st.w = fmaf(z, st.w, 6.0f * x.w);
        T.x = fmaf(zp, st.x, T.x);
        T.y = fmaf(zp, st.y, T.y);
        T.z = fmaf(zp, st.z, T.z);
        T.w = fmaf(zp, st.w, T.w);
        zp *= z;                          // constant-folds under full unroll
    }
    // anticausal sweep over own 20 rows, store
    float4 sm = make_float4(-T.x, -T.y, -T.z, -T.w);
    #pragma unroll
    for (int s = 19; s >= 0; --s) {
        sm.x = z * (sm.x - f[s].x);
        sm.y = z * (sm.y - f[s].y);
        sm.z = z * (sm.z - f[s].z);
        sm.w = z * (sm.w - f[s].w);
        dst[(size_t)(n0 + s) * GPP] = sm;
    }
}

// ---------------- Kernel B: fused axes 3+4, 40-row slab (validated R4) ------
__device__ __forceinline__ int swz(int r, int c) {
    return r * NAX + (c ^ (r & 31));
}

__global__ __launch_bounds__(320, 6)
void slab_d3d4(const float* __restrict__ src, float* __restrict__ dst)
{
    __shared__ float Y[40 * NAX];        // 25.6 KB exchange buffer
    const float z = ZP;
    const int tid = threadIdx.x;         // 0..319
    const int p  = blockIdx.x >> 2;      // plane 0..959
    const int q  = blockIdx.x & 3;       // slab 0..3
    const int R0 = 40 * q;
    const float* pin  = src + (size_t)p * PLN;
    float*       pout = dst + (size_t)p * PLN;

    float f[20];

    // ---- d3: thread (c, h) -> rows R0+20h .. R0+20h+19, column c
    {
        const int c  = tid % NAX;
        const int h  = tid / NAX;        // 0..1
        const int n0 = R0 + 20 * h;
        float st = 0.0f;
        #pragma unroll
        for (int s = 0; s < KW; ++s) {
            int r = n0 - KW + s; if (r < 0) r += NAX;
            st = fmaf(z, st, 6.0f * pin[r * NAX + c]);
        }
        #pragma unroll
        for (int s = 0; s < 20; ++s) {
            st = fmaf(z, st, 6.0f * pin[(n0 + s) * NAX + c]);
            f[s] = st;
        }
        float cpe[KW];
        #pragma unroll
        for (int s = 0; s < KW; ++s) {
            int r = n0 + 20 + s; if (r >= NAX) r -= NAX;
            st = fmaf(z, st, 6.0f * pin[r * NAX + c]);
            cpe[s] = st;
        }
        float sm = 0.0f;
        #pragma unroll
        for (int s = KW - 1; s >= 0; --s) sm = z * (sm - cpe[s]);
        #pragma unroll
        for (int s = 19; s >= 0; --s) { sm = z * (sm - f[s]); f[s] = sm; }

        const int lr0 = 20 * h;
        #pragma unroll
        for (int s = 0; s < 20; ++s)
            Y[swz(lr0 + s, c)] = f[s];
    }
    __syncthreads();

    // ---- d4: thread (rr, mq) -> slab row rr, columns 20mq .. 20mq+19
    {
        const int rr = tid % 40;
        const int mq = tid / 40;         // 0..7
        const int m0 = 20 * mq;
        float st = 0.0f;
        #pragma unroll
        for (int s = 0; s < KW; ++s) {
            int cc = m0 - KW + s; if (cc < 0) cc += NAX;
            st = fmaf(z, st, 6.0f * Y[swz(rr, cc)]);
        }
        #pragma unroll
        for (int s = 0; s < 20; ++s) {
            st = fmaf(z, st, 6.0f * Y[swz(rr, m0 + s)]);
            f[s] = st;
        }
        float cpe[KW];
        #pragma unroll
        for (int s = 0; s < KW; ++s) {
            int cc = m0 + 20 + s; if (cc >= NAX) cc -= NAX;
            st = fmaf(z, st, 6.0f * Y[swz(rr, cc)]);
            cpe[s] = st;
        }
        float sm = 0.0f;
        #pragma unroll
        for (int s = KW - 1; s >= 0; --s) sm = z * (sm - cpe[s]);
        #pragma unroll
        for (int s = 19; s >= 0; --s) { sm = z * (sm - f[s]); f[s] = sm; }

        __syncthreads();                 // all Y reads done before overwrite
        #pragma unroll
        for (int s = 0; s < 20; ++s)
            Y[swz(rr, m0 + s)] = f[s];
    }
    __syncthreads();

    // ---- coalesced store of the slab
    #pragma unroll
    for (int k = 0; k < 20; ++k) {
        const int idx = tid + 320 * k;
        const int lr  = idx / NAX;
        const int c   = idx - lr * NAX;
        pout[(R0 + lr) * NAX + c] = Y[swz(lr, c)];
    }
}

// ---------------- Fallback: R3-validated in-place full-plane kernel ---------
__global__ __launch_bounds__(640, 2)
void pass_d3d4(float* __restrict__ buf)
{
    __shared__ float P[PLN];
    const float z = ZP;
    const int tid = threadIdx.x;
    float* plane = buf + (size_t)blockIdx.x * PLN;

    const int c  = tid % NAX;
    const int tq = tid / NAX;
    const int n0 = tq * 40;

    #pragma unroll
    for (int k = 0; k < 40; ++k) {
        const int r = 4 * k + tq;
        P[swz(r, c)] = plane[r * NAX + c];
    }
    __syncthreads();

    float f[40];
    {
        float st = 0.0f;
        #pragma unroll
        for (int s = 0; s < KW; ++s) {
            int r = n0 - KW + s; if (r < 0) r += NAX;
            st = fmaf(z, st, 6.0f * P[swz(r, c)]);
        }
        #pragma unroll
        for (int s = 0; s < 40; ++s) {
            st = fmaf(z, st, 6.0f * P[swz(n0 + s, c)]);
            f[s] = st;
        }
        __syncthreads();
        #pragma unroll
        for (int s = 0; s < 40; ++s) P[swz(n0 + s, c)] = f[s];
        __syncthreads();
        float sm = 0.0f;
        #pragma unroll
        for (int s = KW - 1; s >= 0; --s) {
            int r = n0 + 40 + s; if (r >= NAX) r -= NAX;
            sm = z * (sm - P[swz(r, c)]);
        }
        __syncthreads();
        #pragma unroll
        for (int s = 39; s >= 0; --s) { sm = z * (sm - f[s]); P[swz(n0 + s, c)] = sm; }
        __syncthreads();
    }
    {
        const int rr = c;
        float st = 0.0f;
        #pragma unroll
        for (int s = 0; s < KW; ++s) {
            int cc = n0 - KW + s; if (cc < 0) cc += NAX;
            st = fmaf(z, st, 6.0f * P[swz(rr, cc)]);
        }
        #pragma unroll
        for (int s = 0; s < 40; ++s) {
            st = fmaf(z, st, 6.0f * P[swz(rr, n0 + s)]);
            f[s] = st;
        }
        __syncthreads();
        #pragma unroll
        for (int s = 0; s < 40; ++s) P[swz(rr, n0 + s)] = f[s];
        __syncthreads();
        float sm = 0.0f;
        #pragma unroll
        for (int s = KW - 1; s >= 0; --s) {
            int cc = n0 + 40 + s; if (cc >= NAX) cc -= NAX;
            sm = z * (sm - P[swz(rr, cc)]);
        }
        __syncthreads();
        #pragma unroll
        for (int s = 39; s >= 0; --s) { sm = z * (sm - f[s]); P[swz(rr, n0 + s)] = sm; }
        __syncthreads();
    }
    #pragma unroll
    for (int k = 0; k < 40; ++k) {
        const int r = 4 * k + tq;
        plane[r * NAX + c] = P[swz(r, c)];
    }
}

extern "C" void kernel_launch(void* const* d_in, const int* in_sizes, int n_in,
                              void* d_out, int out_size, void* d_ws, size_t ws_size,
                              hipStream_t stream) {
    (void)in_sizes; (void)n_in; (void)out_size;
    const float* x = (const float*)d_in[0];
    float* out = (float*)d_out;
    float* ws  = (float*)d_ws;

    const size_t need = (size_t)6 * VOL * sizeof(float);   // 98.3 MB intermediate
    if (ws_size >= need) {
        pass_d2  <<<1200, 256, 0, stream>>>(x, ws);    // in -> ws
        slab_d3d4<<<3840, 320, 0, stream>>>(ws, out);  // ws -> out (disjoint)
    } else {
        pass_d2  <<<1200, 256, 0, stream>>>(x, out);
        pass_d3d4<<<960,  640, 0, stream>>>(out);      // validated fallback
    }
}